// Round 13
// baseline (20.229 us; speedup 1.0000x reference)
//
#include <hip/hip_runtime.h>
#include <math.h>

#define SH_C0f 0.28209479177387814f
#define SH_C1f 0.4886025119029199f
#define EPS2D 0.3f
#define NEAR_PLANE 0.01f
#define FAR_PLANE 1e10f
#define ALPHA_MIN (1.0f/255.0f)
#define ALPHA_MAX 0.999f
#define T_EPS 1e-4f
#define TS 8    // tile size (8x8 pixels)
#define NW 8    // waves per raster block (512 threads)

// ---------------- kernel 1: per-gaussian preprocess (inline 4x4 inverse) ---
__global__ void preprocess_kernel(
    const float* __restrict__ means, const float* __restrict__ opac_in,
    const float* __restrict__ scales, const float* __restrict__ quats,
    const float* __restrict__ sh0, const float* __restrict__ shN,
    const float* __restrict__ c2w, const float* __restrict__ Ks,
    const int* __restrict__ wptr, const int* __restrict__ hptr,
    float4* __restrict__ attrs, float4* __restrict__ bounds, int N)
{
    int i = blockIdx.x * blockDim.x + threadIdx.x;
    if (i >= N) return;

    float m[16];
    #pragma unroll
    for (int k = 0; k < 16; k++) m[k] = c2w[k];
    float inv[12];
    inv[0]  =  m[5]*m[10]*m[15] - m[5]*m[11]*m[14] - m[9]*m[6]*m[15] + m[9]*m[7]*m[14] + m[13]*m[6]*m[11] - m[13]*m[7]*m[10];
    inv[4]  = -m[4]*m[10]*m[15] + m[4]*m[11]*m[14] + m[8]*m[6]*m[15] - m[8]*m[7]*m[14] - m[12]*m[6]*m[11] + m[12]*m[7]*m[10];
    inv[8]  =  m[4]*m[9]*m[15]  - m[4]*m[11]*m[13] - m[8]*m[5]*m[15] + m[8]*m[7]*m[13] + m[12]*m[5]*m[11] - m[12]*m[7]*m[9];
    inv[1]  = -m[1]*m[10]*m[15] + m[1]*m[11]*m[14] + m[9]*m[2]*m[15] - m[9]*m[3]*m[14] - m[13]*m[2]*m[11] + m[13]*m[3]*m[10];
    inv[5]  =  m[0]*m[10]*m[15] - m[0]*m[11]*m[14] - m[8]*m[2]*m[15] + m[8]*m[3]*m[14] + m[12]*m[2]*m[11] - m[12]*m[3]*m[10];
    inv[9]  = -m[0]*m[9]*m[15]  + m[0]*m[11]*m[13] + m[8]*m[1]*m[15] - m[8]*m[3]*m[13] - m[12]*m[1]*m[11] + m[12]*m[3]*m[9];
    inv[2]  =  m[1]*m[6]*m[15]  - m[1]*m[7]*m[14]  - m[5]*m[2]*m[15] + m[5]*m[3]*m[14] + m[13]*m[2]*m[7]  - m[13]*m[3]*m[6];
    inv[6]  = -m[0]*m[6]*m[15]  + m[0]*m[7]*m[14]  + m[4]*m[2]*m[15] - m[4]*m[3]*m[14] - m[12]*m[2]*m[7]  + m[12]*m[3]*m[6];
    inv[10] =  m[0]*m[5]*m[15]  - m[0]*m[7]*m[13]  - m[4]*m[1]*m[15] + m[4]*m[3]*m[13] + m[12]*m[1]*m[7]  - m[12]*m[3]*m[5];
    inv[3]  = -m[1]*m[6]*m[11]  + m[1]*m[7]*m[10]  + m[5]*m[2]*m[11] - m[5]*m[3]*m[10] - m[9]*m[2]*m[7]   + m[9]*m[3]*m[6];
    inv[7]  =  m[0]*m[6]*m[11]  - m[0]*m[7]*m[10]  - m[4]*m[2]*m[11] + m[4]*m[3]*m[10] + m[8]*m[2]*m[7]   - m[8]*m[3]*m[6];
    inv[11] = -m[0]*m[5]*m[11]  + m[0]*m[7]*m[9]   + m[4]*m[1]*m[11] - m[4]*m[3]*m[9]  - m[8]*m[1]*m[7]   + m[8]*m[3]*m[5];
    {
        float inv12 = -m[4]*m[9]*m[14] + m[4]*m[10]*m[13] + m[8]*m[5]*m[14] - m[8]*m[6]*m[13] - m[12]*m[5]*m[10] + m[12]*m[6]*m[9];
        float det = m[0]*inv[0] + m[1]*inv[4] + m[2]*inv[8] + m[3]*inv12;
        float r = 1.0f / det;
        #pragma unroll
        for (int k = 0; k < 12; k++) inv[k] *= r;
    }
    const float W00 = inv[0], W01 = inv[1], W02 = inv[2],  t0 = inv[3];
    const float W10 = inv[4], W11 = inv[5], W12 = inv[6],  t1 = inv[7];
    const float W20 = inv[8], W21 = inv[9], W22 = inv[10], t2 = inv[11];

    const float fx = Ks[0], cx = Ks[2], fy = Ks[4], cy = Ks[5];
    const float width = (float)wptr[0], height = (float)hptr[0];

    const float mxx = means[i*3+0], myy = means[i*3+1], mzz = means[i*3+2];

    const float cpx = m[3], cpy = m[7], cpz = m[11];
    float dx = mxx - cpx, dy = myy - cpy, dz = mzz - cpz;
    float dn = sqrtf(dx*dx + dy*dy + dz*dz);
    dx /= dn; dy /= dn; dz /= dn;

    float col[3];
    #pragma unroll
    for (int c = 0; c < 3; c++) {
        float v = SH_C0f * sh0[i*3+c]
                + SH_C1f * (-dy * shN[i*9 + 0*3 + c] + dz * shN[i*9 + 1*3 + c] - dx * shN[i*9 + 2*3 + c])
                + 0.5f;
        col[c] = fmaxf(v, 0.0f);
    }

    const float op = 1.0f / (1.0f + expf(-opac_in[i]));

    float qw = quats[i*4+0], qx = quats[i*4+1], qy = quats[i*4+2], qz = quats[i*4+3];
    float qn = sqrtf(qw*qw + qx*qx + qy*qy + qz*qz);
    qw /= qn; qx /= qn; qy /= qn; qz /= qn;
    const float R00 = 1.f - 2.f*(qy*qy + qz*qz), R01 = 2.f*(qx*qy - qw*qz), R02 = 2.f*(qx*qz + qw*qy);
    const float R10 = 2.f*(qx*qy + qw*qz), R11 = 1.f - 2.f*(qx*qx + qz*qz), R12 = 2.f*(qy*qz - qw*qx);
    const float R20 = 2.f*(qx*qz - qw*qy), R21 = 2.f*(qy*qz + qw*qx), R22 = 1.f - 2.f*(qx*qx + qy*qy);

    const float sx = scales[i*3+0], sy = scales[i*3+1], sz = scales[i*3+2];
    const float M00 = R00*sx, M01 = R01*sy, M02 = R02*sz;
    const float M10 = R10*sx, M11 = R11*sy, M12 = R12*sz;
    const float M20 = R20*sx, M21 = R21*sy, M22 = R22*sz;

    const float S00 = M00*M00 + M01*M01 + M02*M02;
    const float S01 = M00*M10 + M01*M11 + M02*M12;
    const float S02 = M00*M20 + M01*M21 + M02*M22;
    const float S11 = M10*M10 + M11*M11 + M12*M12;
    const float S12 = M10*M20 + M11*M21 + M12*M22;
    const float S22 = M20*M20 + M21*M21 + M22*M22;

    const float tcx = W00*mxx + W01*myy + W02*mzz + t0;
    const float tcy = W10*mxx + W11*myy + W12*mzz + t1;
    const float tcz = W20*mxx + W21*myy + W22*mzz + t2;
    const float rz = 1.0f / tcz;

    const float limx = 1.3f * (0.5f * width / fx);
    const float limy = 1.3f * (0.5f * height / fy);
    const float txz = fminf(fmaxf(tcx * rz, -limx), limx);
    const float tyz = fminf(fmaxf(tcy * rz, -limy), limy);

    const float V00 = W00*S00 + W01*S01 + W02*S02;
    const float V01 = W00*S01 + W01*S11 + W02*S12;
    const float V02 = W00*S02 + W01*S12 + W02*S22;
    const float V10 = W10*S00 + W11*S01 + W12*S02;
    const float V11 = W10*S01 + W11*S11 + W12*S12;
    const float V12 = W10*S02 + W11*S12 + W12*S22;
    const float V20 = W20*S00 + W21*S01 + W22*S02;
    const float V21 = W20*S01 + W21*S11 + W22*S12;
    const float V22 = W20*S02 + W21*S12 + W22*S22;
    const float CC00 = V00*W00 + V01*W01 + V02*W02;
    const float CC01 = V00*W10 + V01*W11 + V02*W12;
    const float CC02 = V00*W20 + V01*W21 + V02*W22;
    const float CC11 = V10*W10 + V11*W11 + V12*W12;
    const float CC12 = V10*W20 + V11*W21 + V12*W22;
    const float CC22 = V20*W20 + V21*W21 + V22*W22;

    const float j00 = fx * rz,  j02 = -fx * txz * rz;
    const float j11 = fy * rz,  j12 = -fy * tyz * rz;

    const float u0 = j00*CC00 + j02*CC02;
    const float u1 = j00*CC01 + j02*CC12;
    const float u2 = j00*CC02 + j02*CC22;
    const float v1 = j11*CC11 + j12*CC12;
    const float v2 = j11*CC12 + j12*CC22;
    const float c2d00 = u0*j00 + u2*j02;
    const float c2d01 = u1*j11 + u2*j12;
    const float c2d11 = v1*j11 + v2*j12;

    const float a  = c2d00 + EPS2D;
    const float bb = c2d01;
    const float cc = c2d11 + EPS2D;
    const float det = a*cc - bb*bb;
    const float det_safe = (det > 0.0f) ? det : 1.0f;
    const float invd = 1.0f / det_safe;

    const bool valid = (tcz > NEAR_PLANE) && (tcz < FAR_PLANE) && (det > 0.0f);

    float rad = 0.0f;
    if (valid && op >= ALPHA_MIN) {
        const float lmax = 0.5f*(a + cc) + sqrtf(fmaxf(0.f, 0.25f*(a - cc)*(a - cc) + bb*bb));
        const float sig_cut = logf(255.0f * op);
        rad = sqrtf(fmaxf(sig_cut, 0.0f) * 2.0f * lmax) * 1.001f + 0.5f;
    }

    const float mx2d = fx * tcx * rz + cx;
    const float my2d = fy * tcy * rz + cy;

    // HALF conic coefficients (exact power-of-two scale)
    attrs[i*3+0] = make_float4(mx2d, my2d, 0.5f * cc * invd, -bb * invd);  // mx, my, A/2, B
    attrs[i*3+1] = make_float4(0.5f * a * invd, op, tcz, rad);             // C/2, op, tz, rad
    attrs[i*3+2] = make_float4(col[0], col[1], col[2], 0.0f);             // r, g, b
    bounds[i]   = make_float4(mx2d, my2d, rad, tcz);                      // + tz for sort
}

// ---- kernel 2: raster (512 thr). wave-local cull (no block syncs) ->
// u64-key stable sort (tz bits | idx, order-preserving since tz>0) ->
// single-pass scaled segmented composite, 8-wide ILP.
__device__ __forceinline__ float eval_alpha(const float4 g0, const float4 g1,
                                            const float px, const float py) {
    const float ddx = px - g0.x;
    const float ddy = py - g0.y;
    const float sg = g0.z*ddx*ddx + g1.x*ddy*ddy + g0.w*ddx*ddy;
    float a = g1.y * expf(-sg);
    return ((sg >= 0.0f) && (a >= ALPHA_MIN)) ? fminf(a, ALPHA_MAX) : 0.0f;
}

__global__ __launch_bounds__(512) void raster_kernel(
    const float4* __restrict__ attrs, const float4* __restrict__ bounds,
    float* __restrict__ out, int N, int P, const int* __restrict__ wptr)
{
    // dynamic LDS: s_key[NW*SLICE] (u64, gapped per wave) | s_sorted[N] (int)
    extern __shared__ unsigned long long s_key[];
    const int SLICE = (N + NW - 1) / NW;
    int* s_sorted = (int*)(s_key + NW * SLICE);
    __shared__ int   s_cnt[NW];
    __shared__ float s_P[NW][64];
    __shared__ float s_red[NW][64][5];

    const int width  = wptr[0];
    const int height = P / width;
    const int tilesX = (width  + TS - 1) / TS;
    const int tilesY = (height + TS - 1) / TS;
    const int nTiles = tilesX * tilesY;
    const int tid  = threadIdx.x;
    const int lane = tid & 63;
    const int wv   = tid >> 6;

    for (int tile = blockIdx.x; tile < nTiles; tile += gridDim.x) {
        __syncthreads();   // protect smem reuse across grid-stride iterations

        const int tx = tile % tilesX, ty = tile / tilesX;
        const float x0 = (float)(tx*TS) + 0.5f;
        const float x1 = (float)(min(tx*TS + TS - 1, width  - 1)) + 0.5f;
        const float y0 = (float)(ty*TS) + 0.5f;
        const float y1 = (float)(min(ty*TS + TS - 1, height - 1)) + 0.5f;

        // ---- wave-local cull over own index slice (NO block syncs) --------
        {
            const int sstart = wv * SLICE;
            const int send   = min(sstart + SLICE, N);
            int cnt = 0;
            for (int base = sstart; base < send; base += 64) {
                const int j = base + lane;
                bool pred = false;
                unsigned long long key = 0;
                if (j < send) {
                    const float4 b = bounds[j];        // mx, my, rad, tz
                    pred = (b.z > 0.0f) &&
                           (b.x + b.z >= x0) && (b.x - b.z <= x1) &&
                           (b.y + b.z >= y0) && (b.y - b.z <= y1);
                    // tz > NEAR_PLANE > 0 for all pred=true: float bits are
                    // order-preserving; idx tiebreak makes keys unique.
                    key = ((unsigned long long)__float_as_uint(b.w) << 32)
                        | (unsigned int)j;
                }
                const unsigned long long m = __ballot(pred);
                const int pre = __popcll(m & ((1ull << lane) - 1ull));
                if (pred) s_key[sstart + cnt + pre] = key;
                cnt += (int)__popcll(m);
            }
            if (lane == 0) s_cnt[wv] = cnt;
        }
        __syncthreads();

        // ---- counts & prefix (each thread computes locally) ---------------
        int count = 0;
        int prefix[NW];
        #pragma unroll
        for (int w = 0; w < NW; w++) { prefix[w] = count; count += s_cnt[w]; }

        // ---- stable rank sort via u64 keys (all 512 threads, 8-wide) ------
        for (int t = tid; t < count; t += 512) {
            int w = 0;
            #pragma unroll
            for (int q = 1; q < NW; q++) w += (t >= prefix[q]);
            const unsigned long long ke = s_key[w * SLICE + (t - prefix[w])];
            int rank = 0;
            #pragma unroll 1
            for (int w2 = 0; w2 < NW; w2++) {
                const int b2 = w2 * SLICE;
                const int c2 = s_cnt[w2];
                int p2 = 0;
                for (; p2 + 7 < c2; p2 += 8) {       // wave-uniform addrs: LDS broadcast
                    #pragma unroll
                    for (int u = 0; u < 8; u++)
                        rank += (s_key[b2 + p2 + u] < ke);
                }
                for (; p2 < c2; p2++)
                    rank += (s_key[b2 + p2] < ke);
            }
            s_sorted[rank] = (int)(ke & 0xffffffffu);
        }
        __syncthreads();

        // ---- pixel for this lane
        const int px_i = tx*TS + (lane & (TS-1));
        const int py_i = ty*TS + (lane >> 3);
        const bool active = (px_i < width) && (py_i < height);
        const float px = (float)px_i + 0.5f;
        const float py = (float)py_i + 0.5f;

        // ---- segmented single-pass scaled composite (8-wide ILP) ----------
        const int seg    = (count + NW - 1) / NW;
        const int cstart = wv * seg;
        const int cend   = min(cstart + seg, count);

        float Tl = 1.0f;
        float accr = 0.f, accg = 0.f, accb = 0.f, accd = 0.f, acca = 0.f;
        for (int p = cstart; p < cend; p += 8) {
            int id[8];
            float al[8];
            float4 G1[8], G2[8];
            #pragma unroll
            for (int u = 0; u < 8; u++)
                id[u] = s_sorted[(p+u < cend) ? (p+u) : p];
            #pragma unroll
            for (int u = 0; u < 8; u++) {
                const int idx = __builtin_amdgcn_readfirstlane(id[u]);
                const float4 g0 = attrs[idx*3+0];      // uniform -> s_load
                G1[u] = attrs[idx*3+1];
                G2[u] = attrs[idx*3+2];
                const float a = eval_alpha(g0, G1[u], px, py);
                al[u] = (p+u < cend) ? a : 0.0f;
            }
            #pragma unroll
            for (int u = 0; u < 8; u++) {
                const float w = al[u] * Tl;
                accr += w * G2[u].x;
                accg += w * G2[u].y;
                accb += w * G2[u].z;
                accd += w * G1[u].z;
                acca += w;
                Tl *= (1.0f - al[u]);
            }
            if (__all(Tl <= T_EPS)) break;   // tail terms telescope to <= T_EPS
        }
        s_P[wv][lane] = Tl;
        __syncthreads();

        float Ts = active ? 1.0f : 0.0f;
        for (int m = 0; m < wv; m++) Ts *= s_P[m][lane];

        s_red[wv][lane][0] = accr * Ts;
        s_red[wv][lane][1] = accg * Ts;
        s_red[wv][lane][2] = accb * Ts;
        s_red[wv][lane][3] = accd * Ts;
        s_red[wv][lane][4] = acca * Ts;
        __syncthreads();

        if (wv == 0 && active) {
            float r = 0.f, g = 0.f, b = 0.f, d = 0.f, a = 0.f;
            #pragma unroll
            for (int m = 0; m < NW; m++) {
                r += s_red[m][lane][0];
                g += s_red[m][lane][1];
                b += s_red[m][lane][2];
                d += s_red[m][lane][3];
                a += s_red[m][lane][4];
            }
            const int pix = py_i * width + px_i;
            out[pix*4 + 0] = r;
            out[pix*4 + 1] = g;
            out[pix*4 + 2] = b;
            out[pix*4 + 3] = d / fmaxf(a, 1e-10f);
            out[(size_t)P*4 + pix] = a;
        }
    }
}

// ---------------- host-side launch ----------------
extern "C" void kernel_launch(void* const* d_in, const int* in_sizes, int n_in,
                              void* d_out, int out_size, void* d_ws, size_t ws_size,
                              hipStream_t stream) {
    const float* means   = (const float*)d_in[0];
    const float* opac    = (const float*)d_in[1];
    const float* scales  = (const float*)d_in[2];
    const float* quats   = (const float*)d_in[3];
    const float* sh0     = (const float*)d_in[4];
    const float* shN     = (const float*)d_in[5];
    const float* c2w     = (const float*)d_in[6];
    const float* Ks      = (const float*)d_in[7];
    const int*   wptr    = (const int*)d_in[8];
    const int*   hptr    = (const int*)d_in[9];

    const int N = in_sizes[0] / 3;
    const int P = out_size / 5;

    float4* attrs  = (float4*)d_ws;                   // 3*N float4
    float4* bounds = attrs + 3*N;                     // N float4

    const int gb = (N + 255) / 256;
    hipLaunchKernelGGL(preprocess_kernel, dim3(gb), dim3(256), 0, stream,
                       means, opac, scales, quats, sh0, shN, c2w, Ks, wptr, hptr,
                       attrs, bounds, N);

    const int SLICE = (N + NW - 1) / NW;
    const size_t lds = (size_t)NW * SLICE * sizeof(unsigned long long)
                     + (size_t)N * sizeof(int);
    hipLaunchKernelGGL(raster_kernel, dim3(512), dim3(512), lds, stream,
                       attrs, bounds, (float*)d_out, N, P, wptr);
}

// Round 14
// 19.504 us; speedup vs baseline: 1.0372x; 1.0372x over previous
//
#include <hip/hip_runtime.h>
#include <math.h>

#define SH_C0f 0.28209479177387814f
#define SH_C1f 0.4886025119029199f
#define EPS2D 0.3f
#define NEAR_PLANE 0.01f
#define FAR_PLANE 1e10f
#define ALPHA_MIN (1.0f/255.0f)
#define ALPHA_MAX 0.999f
#define T_EPS 1e-4f
#define TS 8    // tile size (8x8 pixels)
#define NW 8    // waves per raster block (512 threads)

// ---------------- kernel 1: per-gaussian preprocess (inline 4x4 inverse) ---
__global__ void preprocess_kernel(
    const float* __restrict__ means, const float* __restrict__ opac_in,
    const float* __restrict__ scales, const float* __restrict__ quats,
    const float* __restrict__ sh0, const float* __restrict__ shN,
    const float* __restrict__ c2w, const float* __restrict__ Ks,
    const int* __restrict__ wptr, const int* __restrict__ hptr,
    float4* __restrict__ attrs, float4* __restrict__ bounds, int N)
{
    int i = blockIdx.x * blockDim.x + threadIdx.x;
    if (i >= N) return;

    float m[16];
    #pragma unroll
    for (int k = 0; k < 16; k++) m[k] = c2w[k];
    float inv[12];
    inv[0]  =  m[5]*m[10]*m[15] - m[5]*m[11]*m[14] - m[9]*m[6]*m[15] + m[9]*m[7]*m[14] + m[13]*m[6]*m[11] - m[13]*m[7]*m[10];
    inv[4]  = -m[4]*m[10]*m[15] + m[4]*m[11]*m[14] + m[8]*m[6]*m[15] - m[8]*m[7]*m[14] - m[12]*m[6]*m[11] + m[12]*m[7]*m[10];
    inv[8]  =  m[4]*m[9]*m[15]  - m[4]*m[11]*m[13] - m[8]*m[5]*m[15] + m[8]*m[7]*m[13] + m[12]*m[5]*m[11] - m[12]*m[7]*m[9];
    inv[1]  = -m[1]*m[10]*m[15] + m[1]*m[11]*m[14] + m[9]*m[2]*m[15] - m[9]*m[3]*m[14] - m[13]*m[2]*m[11] + m[13]*m[3]*m[10];
    inv[5]  =  m[0]*m[10]*m[15] - m[0]*m[11]*m[14] - m[8]*m[2]*m[15] + m[8]*m[3]*m[14] + m[12]*m[2]*m[11] - m[12]*m[3]*m[10];
    inv[9]  = -m[0]*m[9]*m[15]  + m[0]*m[11]*m[13] + m[8]*m[1]*m[15] - m[8]*m[3]*m[13] - m[12]*m[1]*m[11] + m[12]*m[3]*m[9];
    inv[2]  =  m[1]*m[6]*m[15]  - m[1]*m[7]*m[14]  - m[5]*m[2]*m[15] + m[5]*m[3]*m[14] + m[13]*m[2]*m[7]  - m[13]*m[3]*m[6];
    inv[6]  = -m[0]*m[6]*m[15]  + m[0]*m[7]*m[14]  + m[4]*m[2]*m[15] - m[4]*m[3]*m[14] - m[12]*m[2]*m[7]  + m[12]*m[3]*m[6];
    inv[10] =  m[0]*m[5]*m[15]  - m[0]*m[7]*m[13]  - m[4]*m[1]*m[15] + m[4]*m[3]*m[13] + m[12]*m[1]*m[7]  - m[12]*m[3]*m[5];
    inv[3]  = -m[1]*m[6]*m[11]  + m[1]*m[7]*m[10]  + m[5]*m[2]*m[11] - m[5]*m[3]*m[10] - m[9]*m[2]*m[7]   + m[9]*m[3]*m[6];
    inv[7]  =  m[0]*m[6]*m[11]  - m[0]*m[7]*m[10]  - m[4]*m[2]*m[11] + m[4]*m[3]*m[10] + m[8]*m[2]*m[7]   - m[8]*m[3]*m[6];
    inv[11] = -m[0]*m[5]*m[11]  + m[0]*m[7]*m[9]   + m[4]*m[1]*m[11] - m[4]*m[3]*m[9]  - m[8]*m[1]*m[7]   + m[8]*m[3]*m[5];
    {
        float inv12 = -m[4]*m[9]*m[14] + m[4]*m[10]*m[13] + m[8]*m[5]*m[14] - m[8]*m[6]*m[13] - m[12]*m[5]*m[10] + m[12]*m[6]*m[9];
        float det = m[0]*inv[0] + m[1]*inv[4] + m[2]*inv[8] + m[3]*inv12;
        float r = 1.0f / det;
        #pragma unroll
        for (int k = 0; k < 12; k++) inv[k] *= r;
    }
    const float W00 = inv[0], W01 = inv[1], W02 = inv[2],  t0 = inv[3];
    const float W10 = inv[4], W11 = inv[5], W12 = inv[6],  t1 = inv[7];
    const float W20 = inv[8], W21 = inv[9], W22 = inv[10], t2 = inv[11];

    const float fx = Ks[0], cx = Ks[2], fy = Ks[4], cy = Ks[5];
    const float width = (float)wptr[0], height = (float)hptr[0];

    const float mxx = means[i*3+0], myy = means[i*3+1], mzz = means[i*3+2];

    const float cpx = m[3], cpy = m[7], cpz = m[11];
    float dx = mxx - cpx, dy = myy - cpy, dz = mzz - cpz;
    float dn = sqrtf(dx*dx + dy*dy + dz*dz);
    dx /= dn; dy /= dn; dz /= dn;

    float col[3];
    #pragma unroll
    for (int c = 0; c < 3; c++) {
        float v = SH_C0f * sh0[i*3+c]
                + SH_C1f * (-dy * shN[i*9 + 0*3 + c] + dz * shN[i*9 + 1*3 + c] - dx * shN[i*9 + 2*3 + c])
                + 0.5f;
        col[c] = fmaxf(v, 0.0f);
    }

    const float op = 1.0f / (1.0f + expf(-opac_in[i]));

    float qw = quats[i*4+0], qx = quats[i*4+1], qy = quats[i*4+2], qz = quats[i*4+3];
    float qn = sqrtf(qw*qw + qx*qx + qy*qy + qz*qz);
    qw /= qn; qx /= qn; qy /= qn; qz /= qn;
    const float R00 = 1.f - 2.f*(qy*qy + qz*qz), R01 = 2.f*(qx*qy - qw*qz), R02 = 2.f*(qx*qz + qw*qy);
    const float R10 = 2.f*(qx*qy + qw*qz), R11 = 1.f - 2.f*(qx*qx + qz*qz), R12 = 2.f*(qy*qz - qw*qx);
    const float R20 = 2.f*(qx*qz - qw*qy), R21 = 2.f*(qy*qz + qw*qx), R22 = 1.f - 2.f*(qx*qx + qy*qy);

    const float sx = scales[i*3+0], sy = scales[i*3+1], sz = scales[i*3+2];
    const float M00 = R00*sx, M01 = R01*sy, M02 = R02*sz;
    const float M10 = R10*sx, M11 = R11*sy, M12 = R12*sz;
    const float M20 = R20*sx, M21 = R21*sy, M22 = R22*sz;

    const float S00 = M00*M00 + M01*M01 + M02*M02;
    const float S01 = M00*M10 + M01*M11 + M02*M12;
    const float S02 = M00*M20 + M01*M21 + M02*M22;
    const float S11 = M10*M10 + M11*M11 + M12*M12;
    const float S12 = M10*M20 + M11*M21 + M12*M22;
    const float S22 = M20*M20 + M21*M21 + M22*M22;

    const float tcx = W00*mxx + W01*myy + W02*mzz + t0;
    const float tcy = W10*mxx + W11*myy + W12*mzz + t1;
    const float tcz = W20*mxx + W21*myy + W22*mzz + t2;
    const float rz = 1.0f / tcz;

    const float limx = 1.3f * (0.5f * width / fx);
    const float limy = 1.3f * (0.5f * height / fy);
    const float txz = fminf(fmaxf(tcx * rz, -limx), limx);
    const float tyz = fminf(fmaxf(tcy * rz, -limy), limy);

    const float V00 = W00*S00 + W01*S01 + W02*S02;
    const float V01 = W00*S01 + W01*S11 + W02*S12;
    const float V02 = W00*S02 + W01*S12 + W02*S22;
    const float V10 = W10*S00 + W11*S01 + W12*S02;
    const float V11 = W10*S01 + W11*S11 + W12*S12;
    const float V12 = W10*S02 + W11*S12 + W12*S22;
    const float V20 = W20*S00 + W21*S01 + W22*S02;
    const float V21 = W20*S01 + W21*S11 + W22*S12;
    const float V22 = W20*S02 + W21*S12 + W22*S22;
    const float CC00 = V00*W00 + V01*W01 + V02*W02;
    const float CC01 = V00*W10 + V01*W11 + V02*W12;
    const float CC02 = V00*W20 + V01*W21 + V02*W22;
    const float CC11 = V10*W10 + V11*W11 + V12*W12;
    const float CC12 = V10*W20 + V11*W21 + V12*W22;
    const float CC22 = V20*W20 + V21*W21 + V22*W22;

    const float j00 = fx * rz,  j02 = -fx * txz * rz;
    const float j11 = fy * rz,  j12 = -fy * tyz * rz;

    const float u0 = j00*CC00 + j02*CC02;
    const float u1 = j00*CC01 + j02*CC12;
    const float u2 = j00*CC02 + j02*CC22;
    const float v1 = j11*CC11 + j12*CC12;
    const float v2 = j11*CC12 + j12*CC22;
    const float c2d00 = u0*j00 + u2*j02;
    const float c2d01 = u1*j11 + u2*j12;
    const float c2d11 = v1*j11 + v2*j12;

    const float a  = c2d00 + EPS2D;
    const float bb = c2d01;
    const float cc = c2d11 + EPS2D;
    const float det = a*cc - bb*bb;
    const float det_safe = (det > 0.0f) ? det : 1.0f;
    const float invd = 1.0f / det_safe;

    const bool valid = (tcz > NEAR_PLANE) && (tcz < FAR_PLANE) && (det > 0.0f);

    float rad = 0.0f;
    if (valid && op >= ALPHA_MIN) {
        const float lmax = 0.5f*(a + cc) + sqrtf(fmaxf(0.f, 0.25f*(a - cc)*(a - cc) + bb*bb));
        const float sig_cut = logf(255.0f * op);
        rad = sqrtf(fmaxf(sig_cut, 0.0f) * 2.0f * lmax) * 1.001f + 0.5f;
    }

    const float mx2d = fx * tcx * rz + cx;
    const float my2d = fy * tcy * rz + cy;

    // HALF conic coefficients (exact power-of-two scale)
    attrs[i*3+0] = make_float4(mx2d, my2d, 0.5f * cc * invd, -bb * invd);  // mx, my, A/2, B
    attrs[i*3+1] = make_float4(0.5f * a * invd, op, tcz, rad);             // C/2, op, tz, rad
    attrs[i*3+2] = make_float4(col[0], col[1], col[2], 0.0f);             // r, g, b
    bounds[i]   = make_float4(mx2d, my2d, rad, tcz);                      // + tz for sort
}

// ---- kernel 2: raster (512 thr). wave-local cull (no block syncs) ->
// u64-key stable sort (tz bits | idx, order-preserving since tz>0) ->
// single-pass scaled segmented composite (R8/R10 semantics).
__device__ __forceinline__ float eval_alpha(const float4 g0, const float4 g1,
                                            const float px, const float py) {
    const float ddx = px - g0.x;
    const float ddy = py - g0.y;
    const float sg = g0.z*ddx*ddx + g1.x*ddy*ddy + g0.w*ddx*ddy;
    float a = g1.y * expf(-sg);
    return ((sg >= 0.0f) && (a >= ALPHA_MIN)) ? fminf(a, ALPHA_MAX) : 0.0f;
}

__global__ __launch_bounds__(512) void raster_kernel(
    const float4* __restrict__ attrs, const float4* __restrict__ bounds,
    float* __restrict__ out, int N, int P, const int* __restrict__ wptr)
{
    // dynamic LDS: s_key[NW*SLICE] (u64, gapped per wave) | s_sorted[N] (int)
    extern __shared__ unsigned long long s_key[];
    const int SLICE = (N + NW - 1) / NW;
    int* s_sorted = (int*)(s_key + NW * SLICE);
    __shared__ int   s_cnt[NW];
    __shared__ float s_P[NW][64];
    __shared__ float s_red[NW][64][5];

    const int width  = wptr[0];
    const int height = P / width;
    const int tilesX = (width  + TS - 1) / TS;
    const int tilesY = (height + TS - 1) / TS;
    const int nTiles = tilesX * tilesY;
    const int tid  = threadIdx.x;
    const int lane = tid & 63;
    const int wv   = tid >> 6;

    for (int tile = blockIdx.x; tile < nTiles; tile += gridDim.x) {
        __syncthreads();   // protect smem reuse across grid-stride iterations

        const int tx = tile % tilesX, ty = tile / tilesX;
        const float x0 = (float)(tx*TS) + 0.5f;
        const float x1 = (float)(min(tx*TS + TS - 1, width  - 1)) + 0.5f;
        const float y0 = (float)(ty*TS) + 0.5f;
        const float y1 = (float)(min(ty*TS + TS - 1, height - 1)) + 0.5f;

        // ---- wave-local cull over own index slice (NO block syncs) --------
        {
            const int sstart = wv * SLICE;
            const int send   = min(sstart + SLICE, N);
            int cnt = 0;
            for (int base = sstart; base < send; base += 64) {
                const int j = base + lane;
                bool pred = false;
                unsigned long long key = 0;
                if (j < send) {
                    const float4 b = bounds[j];        // mx, my, rad, tz
                    pred = (b.z > 0.0f) &&
                           (b.x + b.z >= x0) && (b.x - b.z <= x1) &&
                           (b.y + b.z >= y0) && (b.y - b.z <= y1);
                    // tz > NEAR_PLANE > 0 for all pred=true: float bits are
                    // order-preserving; idx tiebreak makes keys unique.
                    key = ((unsigned long long)__float_as_uint(b.w) << 32)
                        | (unsigned int)j;
                }
                const unsigned long long m = __ballot(pred);
                const int pre = __popcll(m & ((1ull << lane) - 1ull));
                if (pred) s_key[sstart + cnt + pre] = key;
                cnt += (int)__popcll(m);
            }
            if (lane == 0) s_cnt[wv] = cnt;
        }
        __syncthreads();

        // ---- counts & prefix (each thread computes locally) ---------------
        int count = 0;
        int prefix[NW];
        #pragma unroll
        for (int w = 0; w < NW; w++) { prefix[w] = count; count += s_cnt[w]; }

        // ---- stable rank sort via u64 keys (all 512 threads) --------------
        for (int t = tid; t < count; t += 512) {
            int w = 0;
            #pragma unroll
            for (int q = 1; q < NW; q++) w += (t >= prefix[q]);
            const unsigned long long ke = s_key[w * SLICE + (t - prefix[w])];
            int rank = 0;
            #pragma unroll 1
            for (int w2 = 0; w2 < NW; w2++) {
                const int b2 = w2 * SLICE;
                const int c2 = s_cnt[w2];
                int p2 = 0;
                for (; p2 + 3 < c2; p2 += 4) {       // wave-uniform addrs: LDS broadcast
                    #pragma unroll
                    for (int u = 0; u < 4; u++)
                        rank += (s_key[b2 + p2 + u] < ke);
                }
                for (; p2 < c2; p2++)
                    rank += (s_key[b2 + p2] < ke);
            }
            s_sorted[rank] = (int)(ke & 0xffffffffu);
        }
        __syncthreads();

        // ---- pixel for this lane
        const int px_i = tx*TS + (lane & (TS-1));
        const int py_i = ty*TS + (lane >> 3);
        const bool active = (px_i < width) && (py_i < height);
        const float px = (float)px_i + 0.5f;
        const float py = (float)py_i + 0.5f;

        // ---- segmented single-pass scaled composite (equal segments) ------
        const int seg    = (count + NW - 1) / NW;
        const int cstart = wv * seg;
        const int cend   = min(cstart + seg, count);

        float Tl = 1.0f;
        float accr = 0.f, accg = 0.f, accb = 0.f, accd = 0.f, acca = 0.f;
        for (int p = cstart; p < cend; p += 4) {
            int id[4];
            float al[4];
            float4 G1[4], G2[4];
            #pragma unroll
            for (int u = 0; u < 4; u++)
                id[u] = s_sorted[(p+u < cend) ? (p+u) : p];
            #pragma unroll
            for (int u = 0; u < 4; u++) {
                const int idx = __builtin_amdgcn_readfirstlane(id[u]);
                const float4 g0 = attrs[idx*3+0];
                G1[u] = attrs[idx*3+1];
                G2[u] = attrs[idx*3+2];
                const float a = eval_alpha(g0, G1[u], px, py);
                al[u] = (p+u < cend) ? a : 0.0f;
            }
            #pragma unroll
            for (int u = 0; u < 4; u++) {
                const float w = al[u] * Tl;
                accr += w * G2[u].x;
                accg += w * G2[u].y;
                accb += w * G2[u].z;
                accd += w * G1[u].z;
                acca += w;
                Tl *= (1.0f - al[u]);
            }
            if (__all(Tl <= T_EPS)) break;   // tail terms telescope to <= T_EPS
        }
        s_P[wv][lane] = Tl;
        __syncthreads();

        float Ts = active ? 1.0f : 0.0f;
        for (int m = 0; m < wv; m++) Ts *= s_P[m][lane];

        s_red[wv][lane][0] = accr * Ts;
        s_red[wv][lane][1] = accg * Ts;
        s_red[wv][lane][2] = accb * Ts;
        s_red[wv][lane][3] = accd * Ts;
        s_red[wv][lane][4] = acca * Ts;
        __syncthreads();

        if (wv == 0 && active) {
            float r = 0.f, g = 0.f, b = 0.f, d = 0.f, a = 0.f;
            #pragma unroll
            for (int m = 0; m < NW; m++) {
                r += s_red[m][lane][0];
                g += s_red[m][lane][1];
                b += s_red[m][lane][2];
                d += s_red[m][lane][3];
                a += s_red[m][lane][4];
            }
            const int pix = py_i * width + px_i;
            out[pix*4 + 0] = r;
            out[pix*4 + 1] = g;
            out[pix*4 + 2] = b;
            out[pix*4 + 3] = d / fmaxf(a, 1e-10f);
            out[(size_t)P*4 + pix] = a;
        }
    }
}

// ---------------- host-side launch ----------------
extern "C" void kernel_launch(void* const* d_in, const int* in_sizes, int n_in,
                              void* d_out, int out_size, void* d_ws, size_t ws_size,
                              hipStream_t stream) {
    const float* means   = (const float*)d_in[0];
    const float* opac    = (const float*)d_in[1];
    const float* scales  = (const float*)d_in[2];
    const float* quats   = (const float*)d_in[3];
    const float* sh0     = (const float*)d_in[4];
    const float* shN     = (const float*)d_in[5];
    const float* c2w     = (const float*)d_in[6];
    const float* Ks      = (const float*)d_in[7];
    const int*   wptr    = (const int*)d_in[8];
    const int*   hptr    = (const int*)d_in[9];

    const int N = in_sizes[0] / 3;
    const int P = out_size / 5;

    float4* attrs  = (float4*)d_ws;                   // 3*N float4
    float4* bounds = attrs + 3*N;                     // N float4

    const int gb = (N + 255) / 256;
    hipLaunchKernelGGL(preprocess_kernel, dim3(gb), dim3(256), 0, stream,
                       means, opac, scales, quats, sh0, shN, c2w, Ks, wptr, hptr,
                       attrs, bounds, N);

    const int SLICE = (N + NW - 1) / NW;
    const size_t lds = (size_t)NW * SLICE * sizeof(unsigned long long)
                     + (size_t)N * sizeof(int);
    hipLaunchKernelGGL(raster_kernel, dim3(512), dim3(512), lds, stream,
                       attrs, bounds, (float*)d_out, N, P, wptr);
}